// Round 12
// baseline (450.176 us; speedup 1.0000x reference)
//
#include <hip/hip_runtime.h>
#include <hip/hip_bf16.h>

#define B_ 4
#define C_ 512
#define L_ 2048
#define H_ 8
#define E_ 64
// sqrt(0.125 * log2(e)) — folded into Q (and K=Q) so QK^T yields log2-domain scores
#define QSCALE 0.4246609f
#define NUNITS 512

typedef __attribute__((ext_vector_type(8))) short bf16x8;
typedef __attribute__((ext_vector_type(4))) float f32x4;
typedef __attribute__((ext_vector_type(4))) unsigned short u16x4;

static __device__ __forceinline__ unsigned short f2bf(float f) {
    union { float f; unsigned u; } v; v.f = f;
    unsigned r = v.u + 0x7FFFu + ((v.u >> 16) & 1u);
    return (unsigned short)(r >> 16);
}

// light barrier: make LDS writes visible, do NOT drain vmcnt (loads stay in flight)
#define LBAR() do { asm volatile("s_waitcnt lgkmcnt(0)" ::: "memory"); \
                    __builtin_amdgcn_s_barrier(); } while (0)

// ---------------- Pass A: cast x -> xb (bf16, [b][c][l]) and xt (bf16, [b][l][c]) ----------------
__global__ __launch_bounds__(256) void prep_kernel(const float* __restrict__ x,
                                                   unsigned short* __restrict__ xb,
                                                   unsigned short* __restrict__ xt) {
    const int lt = blockIdx.x, ct = blockIdx.y, b = blockIdx.z;
    const int l0 = lt * 64, c0 = ct * 64;
    const int t = threadIdx.x;
    __shared__ unsigned short T[64 * 72];

    const int cl = t >> 2, lo = (t & 3) * 16;
    const float* src = x + ((size_t)(b * C_ + c0 + cl)) * L_ + l0 + lo;
    unsigned short u[16];
    #pragma unroll
    for (int j = 0; j < 16; j += 4) {
        float4 v = *reinterpret_cast<const float4*>(src + j);
        u[j] = f2bf(v.x); u[j + 1] = f2bf(v.y); u[j + 2] = f2bf(v.z); u[j + 3] = f2bf(v.w);
    }
    unsigned short* xbp = xb + ((size_t)(b * C_ + c0 + cl)) * L_ + l0 + lo;
    reinterpret_cast<uint4*>(xbp)[0] = reinterpret_cast<uint4*>(u)[0];
    reinterpret_cast<uint4*>(xbp)[1] = reinterpret_cast<uint4*>(u)[1];
    reinterpret_cast<uint4*>(&T[cl * 72 + lo])[0] = reinterpret_cast<uint4*>(u)[0];
    reinterpret_cast<uint4*>(&T[cl * 72 + lo + 8])[0] = reinterpret_cast<uint4*>(u)[1];
    __syncthreads();
    const int ll = t >> 2, co = (t & 3) * 16;
    unsigned short v16[16];
    #pragma unroll
    for (int j = 0; j < 16; ++j) v16[j] = T[(co + j) * 72 + ll];
    unsigned short* xtp = xt + ((size_t)b * L_ + l0 + ll) * C_ + c0 + co;
    reinterpret_cast<uint4*>(xtp)[0] = reinterpret_cast<uint4*>(v16)[0];
    reinterpret_cast<uint4*>(xtp)[1] = reinterpret_cast<uint4*>(v16)[1];
}

// ---------------- Pass A2: cast W fp32 -> bf16 ----------------
__global__ __launch_bounds__(256) void wcast_kernel(const float* __restrict__ W,
                                                    unsigned short* __restrict__ Wb) {
    const int i = blockIdx.x * 256 + threadIdx.x;
    float4 v = reinterpret_cast<const float4*>(W)[i];
    union { unsigned short u[4]; unsigned long long ll; } o;
    o.u[0] = f2bf(v.x); o.u[1] = f2bf(v.y); o.u[2] = f2bf(v.z); o.u[3] = f2bf(v.w);
    reinterpret_cast<unsigned long long*>(Wb)[i] = o.ll;
}

// ---------------- Pass B: Q = (W x + b) * QSCALE, bf16 [(b*H+h)][l][e] ----------------
__global__ __launch_bounds__(256) void proj_kernel(const unsigned short* __restrict__ Wb,
                                                   const float* __restrict__ bq,
                                                   const unsigned short* __restrict__ xt,
                                                   unsigned short* __restrict__ qb) {
    const int lt = blockIdx.x, h = blockIdx.y, b = blockIdx.z;
    const int tid = threadIdx.x, w = tid >> 6, lane = tid & 63;
    const int lr = lane & 15, lg = lane >> 4;
    const int l = lt * 64 + w * 16 + lr;
    const int o0 = h * 64;

    f32x4 acc[4] = {};
    const unsigned short* xrow = xt + ((size_t)b * L_ + l) * C_;
    for (int ks = 0; ks < 16; ++ks) {
        bf16x8 bf = *reinterpret_cast<const bf16x8*>(xrow + ks * 32 + lg * 8);
        #pragma unroll
        for (int mt = 0; mt < 4; ++mt) {
            bf16x8 af = *reinterpret_cast<const bf16x8*>(Wb + (size_t)(o0 + mt * 16 + lr) * C_ + ks * 32 + lg * 8);
            acc[mt] = __builtin_amdgcn_mfma_f32_16x16x32_bf16(af, bf, acc[mt], 0, 0, 0);
        }
    }
    const int bh = b * H_ + h;
    unsigned short* qrow = qb + ((size_t)bh * L_ + l) * 64;
    #pragma unroll
    for (int mt = 0; mt < 4; ++mt) {
        const int e0 = mt * 16 + lg * 4;
        const float4 bb = *reinterpret_cast<const float4*>(bq + o0 + e0);
        union { unsigned short u[4]; unsigned long long ll; } o;
        o.u[0] = f2bf((acc[mt][0] + bb.x) * QSCALE);
        o.u[1] = f2bf((acc[mt][1] + bb.y) * QSCALE);
        o.u[2] = f2bf((acc[mt][2] + bb.z) * QSCALE);
        o.u[3] = f2bf((acc[mt][3] + bb.w) * QSCALE);
        *reinterpret_cast<unsigned long long*>(qrow + e0) = o.ll;
    }
}

// ---------------- Pass C: fused S/softmax-sum/PV, QBLK=128, 16 waves, deep V/K pipeline ----------------
// Issue V loads for 32k-phase KS into bank KS (all 4 banks filled during S phase)
#define LDV(KS)                                                                        \
    {                                                                                  \
        _Pragma("unroll")                                                              \
        for (int ct = 0; ct < 2; ++ct)                                                 \
            pvv[KS][ct] = *reinterpret_cast<const bf16x8*>(                            \
                Vbase + (size_t)(c0w + ct * 16 + lr) * L_ + k0 + (KS) * 32 + lg * 8);  \
    }

// Consume bank KS: all 128 P rows (two 64-row halves) x 32 channels = 16 MFMAs
#define PV_USE(KS)                                                                     \
    {                                                                                  \
        _Pragma("unroll")                                                              \
        for (int half = 0; half < 2; ++half) {                                         \
            bf16x8 pa[4];                                                              \
            _Pragma("unroll")                                                          \
            for (int mt = 0; mt < 4; ++mt) {                                           \
                const int row = half * 64 + mt * 16 + lr;                              \
                const int g2 = ((KS) * 4 + lg) ^ lr;                                   \
                pa[mt] = *reinterpret_cast<const bf16x8*>(&Pb[row * 128 + (g2 << 3)]); \
            }                                                                          \
            __builtin_amdgcn_s_setprio(1);                                             \
            _Pragma("unroll")                                                          \
            for (int mt = 0; mt < 4; ++mt)                                             \
                _Pragma("unroll")                                                      \
                for (int ct = 0; ct < 2; ++ct)                                         \
                    acc[half * 4 + mt][ct] = __builtin_amdgcn_mfma_f32_16x16x32_bf16(  \
                        pa[mt], pvv[KS][ct], acc[half * 4 + mt][ct], 0, 0, 0);         \
            __builtin_amdgcn_s_setprio(0);                                             \
        }                                                                              \
    }

__global__ __launch_bounds__(1024, 4) void pv_kernel(const unsigned short* __restrict__ qb,
                                                     const unsigned short* __restrict__ xb,
                                                     float* __restrict__ out,
                                                     int* __restrict__ counter) {
    const int tid = threadIdx.x, w = tid >> 6, lane = tid & 63;
    const int lr = lane & 15, lg = lane >> 4;
    const int sq = w >> 3;                        // S-phase q-half owned by this wave
    const int wk = w & 7;                         // S-phase 16-k subtile
    const int c0w = w * 32;                       // PV: this wave's 32-channel slice

    __shared__ unsigned short Qt[128 * 64];       // swizzled Q tile (16 KB)
    __shared__ unsigned short P2[2][128 * 128];   // double-buffered P, XOR-swizzled (64 KB)
    __shared__ float rsT[128][8];                 // per-k-slab rowsum partials (4 KB)
    __shared__ int s_u;

    for (;;) {
        __syncthreads();   // previous unit's readers of Qt/P2/rsT/s_u are done
        if (tid == 0) s_u = atomicAdd(counter, 1);
        __syncthreads();
        const int u = s_u;
        if (u >= NUNITS) return;

        // heavy q-tiles first (LPT packing on the dynamic queue)
        const int qt = 15 - (u >> 5);
        const int rr = u & 31;
        const int b = rr >> 3, h = rr & 7;
        const int q0 = qt * 128;
        const int nkt = qt + 1;
        const int bh = b * H_ + h;
        const unsigned short* Qbase = qb + (size_t)bh * L_ * 64;
        const unsigned short* Vbase = xb + (size_t)b * C_ * L_;

        // stage Q tile (128 rows) into LDS, granule g -> g ^ (row&7)
        {
            const int r = tid >> 3, g = tid & 7;
            bf16x8 v = *reinterpret_cast<const bf16x8*>(Qbase + (size_t)(q0 + r) * 64 + g * 8);
            *reinterpret_cast<bf16x8*>(&Qt[r * 64 + ((g ^ (r & 7)) << 3)]) = v;
        }

        // prologue K slab for kt=0 (in-loop prefetch covers the rest)
        bf16x8 kb0 = *reinterpret_cast<const bf16x8*>(Qbase + (size_t)(wk * 16 + lr) * 64 + lg * 8);
        bf16x8 kb1 = *reinterpret_cast<const bf16x8*>(Qbase + (size_t)(wk * 16 + lr) * 64 + 32 + lg * 8);

        bf16x8 pvv[4][2];                         // 4 V banks — all loaded during S phase
        f32x4 acc[8][2] = {};
        float rs[4] = {0.f, 0.f, 0.f, 0.f};

        LBAR();   // Qt visible

        #pragma unroll 1
        for (int kt = 0; kt < nkt; ++kt) {
            const int k0 = kt * 128;
            unsigned short* Pb = (unsigned short*)P2[kt & 1];

            // issue ALL V loads for this kt now — consumed after S + LBAR (deep cover)
            LDV(0) LDV(1) LDV(2) LDV(3)

            // S phase: z = K-subtile(wk) x Q(half sq) -> D[k][q], 4 consecutive k/lane
            const int kbase = k0 + wk * 16 + lg * 4;
            #pragma unroll
            for (int nt = 0; nt < 4; ++nt) {
                const int qrow = sq * 64 + nt * 16 + lr;     // row within 128-q tile
                bf16x8 aq0 = *reinterpret_cast<const bf16x8*>(&Qt[qrow * 64 + ((lg ^ (lr & 7)) << 3)]);
                bf16x8 aq1 = *reinterpret_cast<const bf16x8*>(&Qt[qrow * 64 + (((4 + lg) ^ (lr & 7)) << 3)]);
                f32x4 z = {};
                z = __builtin_amdgcn_mfma_f32_16x16x32_bf16(kb0, aq0, z, 0, 0, 0);
                z = __builtin_amdgcn_mfma_f32_16x16x32_bf16(kb1, aq1, z, 0, 0, 0);
                const int q = q0 + qrow;
                const float p0 = (kbase + 0 <= q) ? exp2f(z[0]) : 0.f;
                const float p1 = (kbase + 1 <= q) ? exp2f(z[1]) : 0.f;
                const float p2 = (kbase + 2 <= q) ? exp2f(z[2]) : 0.f;
                const float p3 = (kbase + 3 <= q) ? exp2f(z[3]) : 0.f;
                rs[nt] += (p0 + p1) + (p2 + p3);
                unsigned r01, r23;
                asm("v_cvt_pk_bf16_f32 %0, %1, %2" : "=v"(r01) : "v"(p0), "v"(p1));
                asm("v_cvt_pk_bf16_f32 %0, %1, %2" : "=v"(r23) : "v"(p2), "v"(p3));
                const int col = wk * 16 + lg * 4;
                const int gg = (col >> 3) ^ lr;              // row&15 == lr
                const unsigned long long pk = ((unsigned long long)r23 << 32) | r01;
                *reinterpret_cast<unsigned long long*>(&Pb[qrow * 128 + (gg << 3) + (col & 7)]) = pk;
            }
            LBAR();   // P visible; V loads + K prefetch stay in flight

            // PV: 4 phases x 16 MFMAs, all operands prefetched ≥1 phase ahead
            PV_USE(0)
            if (kt + 1 < nkt) {   // prefetch next kt's K slab under PV steps 1-3
                const size_t krow = (size_t)(k0 + 128 + wk * 16 + lr) * 64;
                kb0 = *reinterpret_cast<const bf16x8*>(Qbase + krow + lg * 8);
                kb1 = *reinterpret_cast<const bf16x8*>(Qbase + krow + 32 + lg * 8);
            }
            PV_USE(1)
            PV_USE(2)
            PV_USE(3)
        }

        // rowsum: reduce over lg (k within subtile), then over the 8 k-slab waves via LDS
        #pragma unroll
        for (int nt = 0; nt < 4; ++nt) {
            float t0 = __shfl_xor(rs[nt], 16); rs[nt] += t0;
            float t1 = __shfl_xor(rs[nt], 32); rs[nt] += t1;
        }
        if (lg == 0) {
            #pragma unroll
            for (int nt = 0; nt < 4; ++nt) rsT[sq * 64 + nt * 16 + lr][wk] = rs[nt];
        }
        LBAR();

        // epilogue: li for all 128 rows, bf16 residual, NT streaming stores
        const unsigned short* xres = xb + (size_t)b * C_ * L_;
        float* ob = out + (size_t)bh * C_ * L_;
        #pragma unroll
        for (int mt = 0; mt < 8; ++mt) {
            const int rowb = mt * 16 + lg * 4;
            f32x4 li;
            #pragma unroll
            for (int r = 0; r < 4; ++r) {
                const f32x4 s0 = *reinterpret_cast<const f32x4*>(&rsT[rowb + r][0]);
                const f32x4 s1 = *reinterpret_cast<const f32x4*>(&rsT[rowb + r][4]);
                li[r] = 1.f / (((s0[0] + s0[1]) + (s0[2] + s0[3])) + ((s1[0] + s1[1]) + (s1[2] + s1[3])));
            }
            const int lbase = q0 + rowb;
            #pragma unroll
            for (int ct = 0; ct < 2; ++ct) {
                const int c = c0w + ct * 16 + lr;
                const u16x4 rv = __builtin_nontemporal_load(
                    reinterpret_cast<const u16x4*>(xres + (size_t)c * L_ + lbase));
                f32x4 o;
                o[0] = acc[mt][ct][0] * li[0] + __uint_as_float((unsigned)rv[0] << 16);
                o[1] = acc[mt][ct][1] * li[1] + __uint_as_float((unsigned)rv[1] << 16);
                o[2] = acc[mt][ct][2] * li[2] + __uint_as_float((unsigned)rv[2] << 16);
                o[3] = acc[mt][ct][3] * li[3] + __uint_as_float((unsigned)rv[3] << 16);
                __builtin_nontemporal_store(o, reinterpret_cast<f32x4*>(ob + (size_t)c * L_ + lbase));
            }
        }
    }
}

extern "C" void kernel_launch(void* const* d_in, const int* in_sizes, int n_in,
                              void* d_out, int out_size, void* d_ws, size_t ws_size,
                              hipStream_t stream) {
    const float* x  = (const float*)d_in[0];
    const float* Wq = (const float*)d_in[1];
    const float* bq = (const float*)d_in[2];
    float* out = (float*)d_out;

    unsigned short* xb   = (unsigned short*)d_ws;                        // B*C*L bf16   = 8 MiB
    unsigned short* xt   = xb + (size_t)B_ * C_ * L_;                    // B*L*C bf16   = 8 MiB
    unsigned short* qbuf = xt + (size_t)B_ * L_ * C_;                    // B*H*L*E bf16 = 8 MiB
    unsigned short* Wb   = qbuf + (size_t)B_ * H_ * L_ * E_;             // 512 KiB
    int* counter = (int*)(Wb + (size_t)H_ * E_ * C_);                    // 4 B

    (void)hipMemsetAsync(counter, 0, 4, stream);
    prep_kernel<<<dim3(32, 8, 4), 256, 0, stream>>>(x, xb, xt);
    wcast_kernel<<<dim3(256), 256, 0, stream>>>(Wq, Wb);
    proj_kernel<<<dim3(32, 8, 4), 256, 0, stream>>>(Wb, bq, xt, qbuf);
    pv_kernel<<<dim3(256), 1024, 0, stream>>>(qbuf, xb, out, counter);
}

// Round 13
// 344.536 us; speedup vs baseline: 1.3066x; 1.3066x over previous
//
#include <hip/hip_runtime.h>
#include <hip/hip_bf16.h>

#define B_ 4
#define C_ 512
#define L_ 2048
#define H_ 8
#define E_ 64
// sqrt(0.125 * log2(e)) — folded into Q (and K=Q) so QK^T yields log2-domain scores
#define QSCALE 0.4246609f
#define NUNITS 1024

typedef __attribute__((ext_vector_type(8))) short bf16x8;
typedef __attribute__((ext_vector_type(4))) float f32x4;
typedef __attribute__((ext_vector_type(4))) unsigned short u16x4;

static __device__ __forceinline__ unsigned short f2bf(float f) {
    union { float f; unsigned u; } v; v.f = f;
    unsigned r = v.u + 0x7FFFu + ((v.u >> 16) & 1u);
    return (unsigned short)(r >> 16);
}

// light barrier: make LDS writes visible, do NOT drain vmcnt (loads stay in flight)
#define LBAR() do { asm volatile("s_waitcnt lgkmcnt(0)" ::: "memory"); \
                    __builtin_amdgcn_s_barrier(); } while (0)

// ---------------- Pass A: cast x -> xb (bf16, [b][c][l]) and xt (bf16, [b][l][c]) ----------------
__global__ __launch_bounds__(256) void prep_kernel(const float* __restrict__ x,
                                                   unsigned short* __restrict__ xb,
                                                   unsigned short* __restrict__ xt) {
    const int lt = blockIdx.x, ct = blockIdx.y, b = blockIdx.z;
    const int l0 = lt * 64, c0 = ct * 64;
    const int t = threadIdx.x;
    __shared__ unsigned short T[64 * 72];

    const int cl = t >> 2, lo = (t & 3) * 16;
    const float* src = x + ((size_t)(b * C_ + c0 + cl)) * L_ + l0 + lo;
    unsigned short u[16];
    #pragma unroll
    for (int j = 0; j < 16; j += 4) {
        float4 v = *reinterpret_cast<const float4*>(src + j);
        u[j] = f2bf(v.x); u[j + 1] = f2bf(v.y); u[j + 2] = f2bf(v.z); u[j + 3] = f2bf(v.w);
    }
    unsigned short* xbp = xb + ((size_t)(b * C_ + c0 + cl)) * L_ + l0 + lo;
    reinterpret_cast<uint4*>(xbp)[0] = reinterpret_cast<uint4*>(u)[0];
    reinterpret_cast<uint4*>(xbp)[1] = reinterpret_cast<uint4*>(u)[1];
    reinterpret_cast<uint4*>(&T[cl * 72 + lo])[0] = reinterpret_cast<uint4*>(u)[0];
    reinterpret_cast<uint4*>(&T[cl * 72 + lo + 8])[0] = reinterpret_cast<uint4*>(u)[1];
    __syncthreads();
    const int ll = t >> 2, co = (t & 3) * 16;
    unsigned short v16[16];
    #pragma unroll
    for (int j = 0; j < 16; ++j) v16[j] = T[(co + j) * 72 + ll];
    unsigned short* xtp = xt + ((size_t)b * L_ + l0 + ll) * C_ + c0 + co;
    reinterpret_cast<uint4*>(xtp)[0] = reinterpret_cast<uint4*>(v16)[0];
    reinterpret_cast<uint4*>(xtp)[1] = reinterpret_cast<uint4*>(v16)[1];
}

// ---------------- Pass A2: cast W fp32 -> bf16 ----------------
__global__ __launch_bounds__(256) void wcast_kernel(const float* __restrict__ W,
                                                    unsigned short* __restrict__ Wb) {
    const int i = blockIdx.x * 256 + threadIdx.x;
    float4 v = reinterpret_cast<const float4*>(W)[i];
    union { unsigned short u[4]; unsigned long long ll; } o;
    o.u[0] = f2bf(v.x); o.u[1] = f2bf(v.y); o.u[2] = f2bf(v.z); o.u[3] = f2bf(v.w);
    reinterpret_cast<unsigned long long*>(Wb)[i] = o.ll;
}

// ---------------- Pass B: Q = (W x + b) * QSCALE, bf16 [(b*H+h)][l][e] ----------------
__global__ __launch_bounds__(256) void proj_kernel(const unsigned short* __restrict__ Wb,
                                                   const float* __restrict__ bq,
                                                   const unsigned short* __restrict__ xt,
                                                   unsigned short* __restrict__ qb) {
    const int lt = blockIdx.x, h = blockIdx.y, b = blockIdx.z;
    const int tid = threadIdx.x, w = tid >> 6, lane = tid & 63;
    const int lr = lane & 15, lg = lane >> 4;
    const int l = lt * 64 + w * 16 + lr;
    const int o0 = h * 64;

    f32x4 acc[4] = {};
    const unsigned short* xrow = xt + ((size_t)b * L_ + l) * C_;
    for (int ks = 0; ks < 16; ++ks) {
        bf16x8 bf = *reinterpret_cast<const bf16x8*>(xrow + ks * 32 + lg * 8);
        #pragma unroll
        for (int mt = 0; mt < 4; ++mt) {
            bf16x8 af = *reinterpret_cast<const bf16x8*>(Wb + (size_t)(o0 + mt * 16 + lr) * C_ + ks * 32 + lg * 8);
            acc[mt] = __builtin_amdgcn_mfma_f32_16x16x32_bf16(af, bf, acc[mt], 0, 0, 0);
        }
    }
    const int bh = b * H_ + h;
    unsigned short* qrow = qb + ((size_t)bh * L_ + l) * 64;
    #pragma unroll
    for (int mt = 0; mt < 4; ++mt) {
        const int e0 = mt * 16 + lg * 4;
        const float4 bb = *reinterpret_cast<const float4*>(bq + o0 + e0);
        union { unsigned short u[4]; unsigned long long ll; } o;
        o.u[0] = f2bf((acc[mt][0] + bb.x) * QSCALE);
        o.u[1] = f2bf((acc[mt][1] + bb.y) * QSCALE);
        o.u[2] = f2bf((acc[mt][2] + bb.z) * QSCALE);
        o.u[3] = f2bf((acc[mt][3] + bb.w) * QSCALE);
        *reinterpret_cast<unsigned long long*>(qrow + e0) = o.ll;
    }
}

// ---------------- Pass C: producer/consumer fused attention ----------------
// S-producer: wave sw computes its 32k slice of the 64q x 128k S tile at PK0, into P2[BUF]
#define PRODUCE(BUF, PK0)                                                                        \
    {                                                                                            \
        const int kw0 = (PK0) + sw * 32;                                                         \
        if (kw0 <= qlim) {                                                                       \
            bf16x8 kb00, kb01, kb10, kb11;                                                       \
            {                                                                                    \
                const size_t kr0 = (size_t)(kw0 + lr) * 64;                                      \
                const size_t kr1 = (size_t)(kw0 + 16 + lr) * 64;                                 \
                kb00 = *reinterpret_cast<const bf16x8*>(Qbase + kr0 + lg * 8);                   \
                kb01 = *reinterpret_cast<const bf16x8*>(Qbase + kr0 + 32 + lg * 8);              \
                kb10 = *reinterpret_cast<const bf16x8*>(Qbase + kr1 + lg * 8);                   \
                kb11 = *reinterpret_cast<const bf16x8*>(Qbase + kr1 + 32 + lg * 8);              \
            }                                                                                    \
            unsigned short* Pw = (unsigned short*)P2[BUF];                                       \
            _Pragma("unroll")                                                                    \
            for (int nt = 0; nt < 4; ++nt) {                                                     \
                const int qrow = nt * 16 + lr;                                                   \
                bf16x8 aq0 = *reinterpret_cast<const bf16x8*>(&Qt[qrow * 64 + ((lg ^ (lr & 7)) << 3)]);       \
                bf16x8 aq1 = *reinterpret_cast<const bf16x8*>(&Qt[qrow * 64 + (((4 + lg) ^ (lr & 7)) << 3)]); \
                const int q = q0 + qrow;                                                         \
                _Pragma("unroll")                                                                \
                for (int ksub = 0; ksub < 2; ++ksub) {                                           \
                    f32x4 z = {};                                                                \
                    z = __builtin_amdgcn_mfma_f32_16x16x32_bf16(ksub ? kb10 : kb00, aq0, z, 0, 0, 0); \
                    z = __builtin_amdgcn_mfma_f32_16x16x32_bf16(ksub ? kb11 : kb01, aq1, z, 0, 0, 0); \
                    const int kbase = kw0 + ksub * 16 + lg * 4;                                  \
                    const float p0 = (kbase + 0 <= q) ? exp2f(z[0]) : 0.f;                       \
                    const float p1 = (kbase + 1 <= q) ? exp2f(z[1]) : 0.f;                       \
                    const float p2 = (kbase + 2 <= q) ? exp2f(z[2]) : 0.f;                       \
                    const float p3 = (kbase + 3 <= q) ? exp2f(z[3]) : 0.f;                       \
                    rs[nt] += (p0 + p1) + (p2 + p3);                                             \
                    unsigned r01, r23;                                                           \
                    asm("v_cvt_pk_bf16_f32 %0, %1, %2" : "=v"(r01) : "v"(p0), "v"(p1));          \
                    asm("v_cvt_pk_bf16_f32 %0, %1, %2" : "=v"(r23) : "v"(p2), "v"(p3));          \
                    const int kl = sw * 32 + ksub * 16 + lg * 4;                                 \
                    const int gg = (kl >> 3) ^ lr;                                               \
                    const unsigned long long pk = ((unsigned long long)r23 << 32) | r01;         \
                    *reinterpret_cast<unsigned long long*>(&Pw[qrow * 128 + (gg << 3) + (kl & 7)]) = pk; \
                }                                                                                \
            }                                                                                    \
        }                                                                                        \
    }

// PV-consumer: load V bank for 32k step at byte-k offset KOFF
#define LDVB(BANK, KOFF)                                                                \
    {                                                                                   \
        _Pragma("unroll")                                                               \
        for (int ct = 0; ct < 4; ++ct)                                                  \
            pvv[BANK][ct] = *reinterpret_cast<const bf16x8*>(                           \
                Vbase + (size_t)(c0w + ct * 16 + lr) * L_ + (KOFF) + lg * 8);           \
    }

// consume bank CUR for step S, prefetch NXT (next step or next kt's step 0)
#define PV_STEP(CUR, NXT, S)                                                            \
    {                                                                                   \
        const int nl = ((S) + 1 < ksmax) ? k0 + ((S) + 1) * 32 : k0 + 128;              \
        LDVB(NXT, nl)                                                                   \
        bf16x8 pa[4];                                                                   \
        _Pragma("unroll")                                                               \
        for (int mt = 0; mt < 4; ++mt) {                                                \
            const int row = mt * 16 + lr;                                               \
            const int g2 = ((S) * 4 + lg) ^ lr;                                         \
            pa[mt] = *reinterpret_cast<const bf16x8*>(&Pb[row * 128 + (g2 << 3)]);      \
        }                                                                               \
        __builtin_amdgcn_s_setprio(1);                                                  \
        _Pragma("unroll")                                                               \
        for (int mt = 0; mt < 4; ++mt)                                                  \
            _Pragma("unroll")                                                           \
            for (int ct = 0; ct < 4; ++ct)                                              \
                acc[mt][ct] = __builtin_amdgcn_mfma_f32_16x16x32_bf16(                  \
                    pa[mt], pvv[CUR][ct], acc[mt][ct], 0, 0, 0);                        \
        __builtin_amdgcn_s_setprio(0);                                                  \
    }

__global__ __launch_bounds__(768, 3) void pv_kernel(const unsigned short* __restrict__ qb,
                                                    const unsigned short* __restrict__ xb,
                                                    float* __restrict__ out,
                                                    int* __restrict__ counter) {
    const int tid = threadIdx.x, w = tid >> 6, lane = tid & 63;
    const int lr = lane & 15, lg = lane >> 4;
    const bool isS = (w < 4);
    const int sw = w;                            // S-producer k-slice (waves 0-3)
    const int c0w = (w - 4) * 64;                // PV-consumer 64-channel slice (waves 4-11)

    __shared__ unsigned short Qt[64 * 64];       // swizzled Q tile (8 KB)
    __shared__ unsigned short P2[2][64 * 128];   // double-buffered P, XOR-swizzled (32 KB)
    __shared__ float rsT[64][4];                 // per-S-wave rowsum partials (1 KB)
    __shared__ int s_u;

    for (;;) {
        __syncthreads();   // previous unit's readers of Qt/P2/rsT/s_u are done
        if (tid == 0) s_u = atomicAdd(counter, 1);
        __syncthreads();
        const int u = s_u;
        if (u >= NUNITS) return;

        // heavy q-tiles first (LPT packing on the dynamic queue)
        const int qt = 31 - (u >> 5);
        const int rr = u & 31;
        const int b = rr >> 3, h = rr & 7;
        const int q0 = qt * 64, qlim = q0 + 63;
        const int nkt = (q0 >> 7) + 1;
        const int bh = b * H_ + h;
        const unsigned short* Qbase = qb + (size_t)bh * L_ * 64;
        const unsigned short* Vbase = xb + (size_t)b * C_ * L_;

        // stage Q tile (64 rows x 64 e) into LDS, granule g -> g ^ (row&7)
        if (tid < 512) {
            const int r = tid >> 3, g = tid & 7;
            bf16x8 v = *reinterpret_cast<const bf16x8*>(Qbase + (size_t)(q0 + r) * 64 + g * 8);
            *reinterpret_cast<bf16x8*>(&Qt[r * 64 + ((g ^ (r & 7)) << 3)]) = v;
        }

        f32x4 acc[4][4] = {};                    // PV waves only
        float rs[4] = {0.f, 0.f, 0.f, 0.f};      // S waves only
        bf16x8 pvv[2][4];                        // PV: 2-bank V ring

        LBAR();   // Qt visible

        // prologue: S waves produce P[0] for kt=0; PV waves preload V bank 0
        if (isS) {
            PRODUCE(0, 0)
        } else {
            LDVB(0, 0)
        }
        LBAR();   // P[0] visible

        #pragma unroll 1
        for (int kt = 0; kt < nkt; ++kt) {
            const int k0 = kt * 128;
            if (isS) {
                // produce next kt's P while consumers eat this one
                if (kt + 1 < nkt) PRODUCE((kt + 1) & 1, k0 + 128)
            } else {
                const unsigned short* Pb = (const unsigned short*)P2[kt & 1];
                const int ksmax = min(4, ((qlim - k0) >> 5) + 1);   // 2 or 4
                PV_STEP(0, 1, 0)
                PV_STEP(1, 0, 1)
                if (ksmax == 4) {
                    PV_STEP(0, 1, 2)
                    PV_STEP(1, 0, 3)
                }
            }
            LBAR();   // next P visible / this P consumed; global loads stay in flight
        }

        // rowsum: S waves reduce their lane partials and publish
        if (isS) {
            #pragma unroll
            for (int nt = 0; nt < 4; ++nt) {
                float t0 = __shfl_xor(rs[nt], 16); rs[nt] += t0;
                float t1 = __shfl_xor(rs[nt], 32); rs[nt] += t1;
            }
            if (lg == 0) {
                #pragma unroll
                for (int nt = 0; nt < 4; ++nt) rsT[nt * 16 + lr][sw] = rs[nt];
            }
        }
        LBAR();

        // epilogue (PV waves): li per q, bf16 residual, NT streaming stores
        if (!isS) {
            const unsigned short* xres = xb + (size_t)b * C_ * L_;
            float* ob = out + (size_t)bh * C_ * L_;
            #pragma unroll
            for (int mt = 0; mt < 4; ++mt) {
                f32x4 li;
                #pragma unroll
                for (int r = 0; r < 4; ++r) {
                    const f32x4 s4 = *reinterpret_cast<const f32x4*>(&rsT[mt * 16 + lg * 4 + r][0]);
                    li[r] = 1.f / ((s4[0] + s4[1]) + (s4[2] + s4[3]));
                }
                const int lbase = q0 + mt * 16 + lg * 4;
                #pragma unroll
                for (int ct = 0; ct < 4; ++ct) {
                    const int c = c0w + ct * 16 + lr;
                    const u16x4 rv = __builtin_nontemporal_load(
                        reinterpret_cast<const u16x4*>(xres + (size_t)c * L_ + lbase));
                    f32x4 o;
                    o[0] = acc[mt][ct][0] * li[0] + __uint_as_float((unsigned)rv[0] << 16);
                    o[1] = acc[mt][ct][1] * li[1] + __uint_as_float((unsigned)rv[1] << 16);
                    o[2] = acc[mt][ct][2] * li[2] + __uint_as_float((unsigned)rv[2] << 16);
                    o[3] = acc[mt][ct][3] * li[3] + __uint_as_float((unsigned)rv[3] << 16);
                    __builtin_nontemporal_store(o, reinterpret_cast<f32x4*>(ob + (size_t)c * L_ + lbase));
                }
            }
        }
    }
}

extern "C" void kernel_launch(void* const* d_in, const int* in_sizes, int n_in,
                              void* d_out, int out_size, void* d_ws, size_t ws_size,
                              hipStream_t stream) {
    const float* x  = (const float*)d_in[0];
    const float* Wq = (const float*)d_in[1];
    const float* bq = (const float*)d_in[2];
    float* out = (float*)d_out;

    unsigned short* xb   = (unsigned short*)d_ws;                        // B*C*L bf16   = 8 MiB
    unsigned short* xt   = xb + (size_t)B_ * C_ * L_;                    // B*L*C bf16   = 8 MiB
    unsigned short* qbuf = xt + (size_t)B_ * L_ * C_;                    // B*H*L*E bf16 = 8 MiB
    unsigned short* Wb   = qbuf + (size_t)B_ * H_ * L_ * E_;             // 512 KiB
    int* counter = (int*)(Wb + (size_t)H_ * E_ * C_);                    // 4 B

    (void)hipMemsetAsync(counter, 0, 4, stream);
    prep_kernel<<<dim3(32, 8, 4), 256, 0, stream>>>(x, xb, xt);
    wcast_kernel<<<dim3(256), 256, 0, stream>>>(Wq, Wb);
    proj_kernel<<<dim3(32, 8, 4), 256, 0, stream>>>(Wb, bq, xt, qbuf);
    pv_kernel<<<dim3(256), 768, 0, stream>>>(qbuf, xb, out, counter);
}

// Round 14
// 255.971 us; speedup vs baseline: 1.7587x; 1.3460x over previous
//
#include <hip/hip_runtime.h>
#include <hip/hip_bf16.h>

#define B_ 4
#define C_ 512
#define L_ 2048
#define H_ 8
#define E_ 64
// sqrt(0.125 * log2(e)) — folded into Q (and K=Q) so QK^T yields log2-domain scores
#define QSCALE 0.4246609f
#define NUNITS 1024

typedef __attribute__((ext_vector_type(8))) short bf16x8;
typedef __attribute__((ext_vector_type(4))) float f32x4;
typedef __attribute__((ext_vector_type(4))) unsigned short u16x4;

static __device__ __forceinline__ unsigned short f2bf(float f) {
    union { float f; unsigned u; } v; v.f = f;
    unsigned r = v.u + 0x7FFFu + ((v.u >> 16) & 1u);
    return (unsigned short)(r >> 16);
}

// light barrier: make LDS writes visible, do NOT drain vmcnt (loads stay in flight)
#define LBAR() do { asm volatile("s_waitcnt lgkmcnt(0)" ::: "memory"); \
                    __builtin_amdgcn_s_barrier(); } while (0)

// ---------------- Pass A: cast x -> xb (bf16, [b][c][l]) and xt (bf16, [b][l][c]) ----------------
__global__ __launch_bounds__(256) void prep_kernel(const float* __restrict__ x,
                                                   unsigned short* __restrict__ xb,
                                                   unsigned short* __restrict__ xt) {
    const int lt = blockIdx.x, ct = blockIdx.y, b = blockIdx.z;
    const int l0 = lt * 64, c0 = ct * 64;
    const int t = threadIdx.x;
    __shared__ unsigned short T[64 * 72];

    const int cl = t >> 2, lo = (t & 3) * 16;
    const float* src = x + ((size_t)(b * C_ + c0 + cl)) * L_ + l0 + lo;
    unsigned short u[16];
    #pragma unroll
    for (int j = 0; j < 16; j += 4) {
        float4 v = *reinterpret_cast<const float4*>(src + j);
        u[j] = f2bf(v.x); u[j + 1] = f2bf(v.y); u[j + 2] = f2bf(v.z); u[j + 3] = f2bf(v.w);
    }
    unsigned short* xbp = xb + ((size_t)(b * C_ + c0 + cl)) * L_ + l0 + lo;
    reinterpret_cast<uint4*>(xbp)[0] = reinterpret_cast<uint4*>(u)[0];
    reinterpret_cast<uint4*>(xbp)[1] = reinterpret_cast<uint4*>(u)[1];
    reinterpret_cast<uint4*>(&T[cl * 72 + lo])[0] = reinterpret_cast<uint4*>(u)[0];
    reinterpret_cast<uint4*>(&T[cl * 72 + lo + 8])[0] = reinterpret_cast<uint4*>(u)[1];
    __syncthreads();
    const int ll = t >> 2, co = (t & 3) * 16;
    unsigned short v16[16];
    #pragma unroll
    for (int j = 0; j < 16; ++j) v16[j] = T[(co + j) * 72 + ll];
    unsigned short* xtp = xt + ((size_t)b * L_ + l0 + ll) * C_ + c0 + co;
    reinterpret_cast<uint4*>(xtp)[0] = reinterpret_cast<uint4*>(v16)[0];
    reinterpret_cast<uint4*>(xtp)[1] = reinterpret_cast<uint4*>(v16)[1];
}

// ---------------- Pass A2: cast W fp32 -> bf16 ----------------
__global__ __launch_bounds__(256) void wcast_kernel(const float* __restrict__ W,
                                                    unsigned short* __restrict__ Wb) {
    const int i = blockIdx.x * 256 + threadIdx.x;
    float4 v = reinterpret_cast<const float4*>(W)[i];
    union { unsigned short u[4]; unsigned long long ll; } o;
    o.u[0] = f2bf(v.x); o.u[1] = f2bf(v.y); o.u[2] = f2bf(v.z); o.u[3] = f2bf(v.w);
    reinterpret_cast<unsigned long long*>(Wb)[i] = o.ll;
}

// ---------------- Pass B: Q = (W x + b) * QSCALE, bf16 [(b*H+h)][l][e] ----------------
__global__ __launch_bounds__(256) void proj_kernel(const unsigned short* __restrict__ Wb,
                                                   const float* __restrict__ bq,
                                                   const unsigned short* __restrict__ xt,
                                                   unsigned short* __restrict__ qb) {
    const int lt = blockIdx.x, h = blockIdx.y, b = blockIdx.z;
    const int tid = threadIdx.x, w = tid >> 6, lane = tid & 63;
    const int lr = lane & 15, lg = lane >> 4;
    const int l = lt * 64 + w * 16 + lr;
    const int o0 = h * 64;

    f32x4 acc[4] = {};
    const unsigned short* xrow = xt + ((size_t)b * L_ + l) * C_;
    for (int ks = 0; ks < 16; ++ks) {
        bf16x8 bf = *reinterpret_cast<const bf16x8*>(xrow + ks * 32 + lg * 8);
        #pragma unroll
        for (int mt = 0; mt < 4; ++mt) {
            bf16x8 af = *reinterpret_cast<const bf16x8*>(Wb + (size_t)(o0 + mt * 16 + lr) * C_ + ks * 32 + lg * 8);
            acc[mt] = __builtin_amdgcn_mfma_f32_16x16x32_bf16(af, bf, acc[mt], 0, 0, 0);
        }
    }
    const int bh = b * H_ + h;
    unsigned short* qrow = qb + ((size_t)bh * L_ + l) * 64;
    #pragma unroll
    for (int mt = 0; mt < 4; ++mt) {
        const int e0 = mt * 16 + lg * 4;
        const float4 bb = *reinterpret_cast<const float4*>(bq + o0 + e0);
        union { unsigned short u[4]; unsigned long long ll; } o;
        o.u[0] = f2bf((acc[mt][0] + bb.x) * QSCALE);
        o.u[1] = f2bf((acc[mt][1] + bb.y) * QSCALE);
        o.u[2] = f2bf((acc[mt][2] + bb.z) * QSCALE);
        o.u[3] = f2bf((acc[mt][3] + bb.w) * QSCALE);
        *reinterpret_cast<unsigned long long*>(qrow + e0) = o.ll;
    }
}

// ---------------- Pass C: fused attention, KBLK=512 long phases, 8 waves ----------------
// V loads for 32k-step at k-offset KOFF into bank BK (4 x b128, wave's 64 channels)
#define LDVB(BK, KOFF)                                                                  \
    {                                                                                   \
        _Pragma("unroll")                                                               \
        for (int ct = 0; ct < 4; ++ct)                                                  \
            pvv[BK][ct] = *reinterpret_cast<const bf16x8*>(                             \
                Vbase + (size_t)(c0w + ct * 16 + lr) * L_ + (KOFF) + lg * 8);           \
    }

// PV step S_ (runtime): consume bank CUR, prefetch step S_+1 into NXT; 16 MFMAs
#define PV_STEP(CUR, NXT, S_)                                                           \
    {                                                                                   \
        const int s_ = (S_);                                                            \
        if (s_ + 1 < ksmax) LDVB(NXT, k0 + (s_ + 1) * 32)                               \
        bf16x8 pa[4];                                                                   \
        _Pragma("unroll")                                                               \
        for (int mt = 0; mt < 4; ++mt) {                                                \
            const int row = mt * 16 + lr;                                               \
            const int g2 = (s_ * 4 + lg) ^ (lr & 7);                                    \
            pa[mt] = *reinterpret_cast<const bf16x8*>(&P[row * 512 + (g2 << 3)]);       \
        }                                                                               \
        __builtin_amdgcn_s_setprio(1);                                                  \
        _Pragma("unroll")                                                               \
        for (int mt = 0; mt < 4; ++mt)                                                  \
            _Pragma("unroll")                                                           \
            for (int ct = 0; ct < 4; ++ct)                                              \
                acc[mt][ct] = __builtin_amdgcn_mfma_f32_16x16x32_bf16(                  \
                    pa[mt], pvv[CUR][ct], acc[mt][ct], 0, 0, 0);                        \
        __builtin_amdgcn_s_setprio(0);                                                  \
    }

__global__ __launch_bounds__(512, 2) void pv_kernel(const unsigned short* __restrict__ qb,
                                                    const unsigned short* __restrict__ xb,
                                                    float* __restrict__ out,
                                                    int* __restrict__ counter) {
    const int tid = threadIdx.x, w = tid >> 6, lane = tid & 63;
    const int lr = lane & 15, lg = lane >> 4;
    const int c0w = w * 64;                      // PV: this wave's 64-channel slice

    __shared__ unsigned short Qt[64 * 64];       // swizzled Q tile (8 KB)
    __shared__ unsigned short P[64 * 512];       // 64q x 512k bf16, XOR-swizzled (64 KB)
    __shared__ float rsT[64][8];                 // per-S-wave rowsum partials (2 KB)
    __shared__ int s_u;

    for (;;) {
        __syncthreads();   // previous unit's readers of Qt/P/rsT/s_u are done
        if (tid == 0) s_u = atomicAdd(counter, 1);
        __syncthreads();
        const int u = s_u;
        if (u >= NUNITS) return;

        // heavy q-tiles first (LPT packing on the dynamic queue)
        const int qt = 31 - (u >> 5);
        const int rr = u & 31;
        const int b = rr >> 3, h = rr & 7;
        const int q0 = qt * 64, qlim = q0 + 63;
        const int nkt = (q0 >> 9) + 1;           // KBLK = 512
        const int bh = b * H_ + h;
        const unsigned short* Qbase = qb + (size_t)bh * L_ * 64;
        const unsigned short* Vbase = xb + (size_t)b * C_ * L_;

        // stage Q tile (64 rows x 64 e) into LDS, granule g -> g ^ (row&7)
        {
            const int r = tid >> 3, g = tid & 7;
            bf16x8 v = *reinterpret_cast<const bf16x8*>(Qbase + (size_t)(q0 + r) * 64 + g * 8);
            *reinterpret_cast<bf16x8*>(&Qt[r * 64 + ((g ^ (r & 7)) << 3)]) = v;
        }

        bf16x8 pvv[2][4];                        // 2-bank V ring (distance-1 = 16 MFMAs)
        f32x4 acc[4][4] = {};
        float rs[4] = {0.f, 0.f, 0.f, 0.f};

        LBAR();   // Qt visible

        #pragma unroll 1
        for (int kt = 0; kt < nkt; ++kt) {
            const int k0 = kt * 512;
            const int ksmax = min(16, ((qlim - k0) >> 5) + 1);   // even, 2..16
            const int kw0 = k0 + w * 64;                          // S: wave's 64k slice

            // ---- S phase: wave computes 64q x 64k slice of S, exp, pack to P ----
            if (kw0 <= qlim) {
                // K A-frags: 4 ksub x 2 e-halves, direct from global
                bf16x8 kb[4][2];
                #pragma unroll
                for (int ksub = 0; ksub < 4; ++ksub) {
                    const size_t krow = (size_t)(kw0 + ksub * 16 + lr) * 64;
                    kb[ksub][0] = *reinterpret_cast<const bf16x8*>(Qbase + krow + lg * 8);
                    kb[ksub][1] = *reinterpret_cast<const bf16x8*>(Qbase + krow + 32 + lg * 8);
                }
                LDVB(0, k0)   // PV step-0 V loads issued under the S phase
                #pragma unroll
                for (int nt = 0; nt < 4; ++nt) {
                    const int qrow = nt * 16 + lr;
                    bf16x8 aq0 = *reinterpret_cast<const bf16x8*>(&Qt[qrow * 64 + ((lg ^ (lr & 7)) << 3)]);
                    bf16x8 aq1 = *reinterpret_cast<const bf16x8*>(&Qt[qrow * 64 + (((4 + lg) ^ (lr & 7)) << 3)]);
                    const int q = q0 + qrow;
                    #pragma unroll
                    for (int ksub = 0; ksub < 4; ++ksub) {
                        f32x4 z = {};
                        z = __builtin_amdgcn_mfma_f32_16x16x32_bf16(kb[ksub][0], aq0, z, 0, 0, 0);
                        z = __builtin_amdgcn_mfma_f32_16x16x32_bf16(kb[ksub][1], aq1, z, 0, 0, 0);
                        const int kbase = kw0 + ksub * 16 + lg * 4;
                        const float p0 = (kbase + 0 <= q) ? exp2f(z[0]) : 0.f;
                        const float p1 = (kbase + 1 <= q) ? exp2f(z[1]) : 0.f;
                        const float p2 = (kbase + 2 <= q) ? exp2f(z[2]) : 0.f;
                        const float p3 = (kbase + 3 <= q) ? exp2f(z[3]) : 0.f;
                        rs[nt] += (p0 + p1) + (p2 + p3);
                        unsigned r01, r23;
                        asm("v_cvt_pk_bf16_f32 %0, %1, %2" : "=v"(r01) : "v"(p0), "v"(p1));
                        asm("v_cvt_pk_bf16_f32 %0, %1, %2" : "=v"(r23) : "v"(p2), "v"(p3));
                        const int kl = w * 64 + ksub * 16 + lg * 4;   // 0..511
                        const int gg = (kl >> 3) ^ (qrow & 7);
                        const unsigned long long pk = ((unsigned long long)r23 << 32) | r01;
                        *reinterpret_cast<unsigned long long*>(&P[qrow * 512 + (gg << 3) + (kl & 7)]) = pk;
                    }
                }
            } else {
                LDVB(0, k0)
            }
            LBAR();   // P visible; V bank-0 loads stay in flight

            // ---- PV phase: 16 back-to-back steps, no barriers, 2-bank V ring ----
            #pragma unroll 1
            for (int s = 0; s < ksmax; s += 2) {
                PV_STEP(0, 1, s)
                PV_STEP(1, 0, s + 1)
            }
            LBAR();   // P consumed; next kt's S may overwrite
        }

        // rowsum: reduce over lg, publish per-wave partials, merge
        #pragma unroll
        for (int nt = 0; nt < 4; ++nt) {
            float t0 = __shfl_xor(rs[nt], 16); rs[nt] += t0;
            float t1 = __shfl_xor(rs[nt], 32); rs[nt] += t1;
        }
        if (lg == 0) {
            #pragma unroll
            for (int nt = 0; nt < 4; ++nt) rsT[nt * 16 + lr][w] = rs[nt];
        }
        LBAR();

        // epilogue: li per q, bf16 residual, NT streaming stores
        const unsigned short* xres = xb + (size_t)b * C_ * L_;
        float* ob = out + (size_t)bh * C_ * L_;
        #pragma unroll
        for (int mt = 0; mt < 4; ++mt) {
            f32x4 li;
            #pragma unroll
            for (int r = 0; r < 4; ++r) {
                const f32x4 s0 = *reinterpret_cast<const f32x4*>(&rsT[mt * 16 + lg * 4 + r][0]);
                const f32x4 s1 = *reinterpret_cast<const f32x4*>(&rsT[mt * 16 + lg * 4 + r][4]);
                li[r] = 1.f / (((s0[0] + s0[1]) + (s0[2] + s0[3])) + ((s1[0] + s1[1]) + (s1[2] + s1[3])));
            }
            const int lbase = q0 + mt * 16 + lg * 4;
            #pragma unroll
            for (int ct = 0; ct < 4; ++ct) {
                const int c = c0w + ct * 16 + lr;
                const u16x4 rv = __builtin_nontemporal_load(
                    reinterpret_cast<const u16x4*>(xres + (size_t)c * L_ + lbase));
                f32x4 o;
                o[0] = acc[mt][ct][0] * li[0] + __uint_as_float((unsigned)rv[0] << 16);
                o[1] = acc[mt][ct][1] * li[1] + __uint_as_float((unsigned)rv[1] << 16);
                o[2] = acc[mt][ct][2] * li[2] + __uint_as_float((unsigned)rv[2] << 16);
                o[3] = acc[mt][ct][3] * li[3] + __uint_as_float((unsigned)rv[3] << 16);
                __builtin_nontemporal_store(o, reinterpret_cast<f32x4*>(ob + (size_t)c * L_ + lbase));
            }
        }
    }
}

extern "C" void kernel_launch(void* const* d_in, const int* in_sizes, int n_in,
                              void* d_out, int out_size, void* d_ws, size_t ws_size,
                              hipStream_t stream) {
    const float* x  = (const float*)d_in[0];
    const float* Wq = (const float*)d_in[1];
    const float* bq = (const float*)d_in[2];
    float* out = (float*)d_out;

    unsigned short* xb   = (unsigned short*)d_ws;                        // B*C*L bf16   = 8 MiB
    unsigned short* xt   = xb + (size_t)B_ * C_ * L_;                    // B*L*C bf16   = 8 MiB
    unsigned short* qbuf = xt + (size_t)B_ * L_ * C_;                    // B*H*L*E bf16 = 8 MiB
    unsigned short* Wb   = qbuf + (size_t)B_ * H_ * L_ * E_;             // 512 KiB
    int* counter = (int*)(Wb + (size_t)H_ * E_ * C_);                    // 4 B

    (void)hipMemsetAsync(counter, 0, 4, stream);
    prep_kernel<<<dim3(32, 8, 4), 256, 0, stream>>>(x, xb, xt);
    wcast_kernel<<<dim3(256), 256, 0, stream>>>(Wq, Wb);
    proj_kernel<<<dim3(32, 8, 4), 256, 0, stream>>>(Wb, bq, xt, qbuf);
    pv_kernel<<<dim3(512), 512, 0, stream>>>(qbuf, xb, out, counter);
}

// Round 15
// 251.770 us; speedup vs baseline: 1.7880x; 1.0167x over previous
//
#include <hip/hip_runtime.h>
#include <hip/hip_bf16.h>

#define B_ 4
#define C_ 512
#define L_ 2048
#define H_ 8
#define E_ 64
// sqrt(0.125 * log2(e)) — folded into Q (and K=Q) so QK^T yields log2-domain scores
#define QSCALE 0.4246609f
#define NUNITS_B 256   // units per batch: 8 h x 32 qt

typedef __attribute__((ext_vector_type(8))) short bf16x8;
typedef __attribute__((ext_vector_type(4))) float f32x4;
typedef __attribute__((ext_vector_type(4))) unsigned short u16x4;

static __device__ __forceinline__ unsigned short f2bf(float f) {
    union { float f; unsigned u; } v; v.f = f;
    unsigned r = v.u + 0x7FFFu + ((v.u >> 16) & 1u);
    return (unsigned short)(r >> 16);
}

// light barrier: make LDS writes visible, do NOT drain vmcnt (loads stay in flight)
#define LBAR() do { asm volatile("s_waitcnt lgkmcnt(0)" ::: "memory"); \
                    __builtin_amdgcn_s_barrier(); } while (0)

// ---------------- Pass A: cast x -> xb (bf16, [b][c][l]) and xt (bf16, [b][l][c]) ----------------
__global__ __launch_bounds__(256) void prep_kernel(const float* __restrict__ x,
                                                   unsigned short* __restrict__ xb,
                                                   unsigned short* __restrict__ xt) {
    const int lt = blockIdx.x, ct = blockIdx.y, b = blockIdx.z;
    const int l0 = lt * 64, c0 = ct * 64;
    const int t = threadIdx.x;
    __shared__ unsigned short T[64 * 72];

    const int cl = t >> 2, lo = (t & 3) * 16;
    const float* src = x + ((size_t)(b * C_ + c0 + cl)) * L_ + l0 + lo;
    unsigned short u[16];
    #pragma unroll
    for (int j = 0; j < 16; j += 4) {
        float4 v = *reinterpret_cast<const float4*>(src + j);
        u[j] = f2bf(v.x); u[j + 1] = f2bf(v.y); u[j + 2] = f2bf(v.z); u[j + 3] = f2bf(v.w);
    }
    unsigned short* xbp = xb + ((size_t)(b * C_ + c0 + cl)) * L_ + l0 + lo;
    reinterpret_cast<uint4*>(xbp)[0] = reinterpret_cast<uint4*>(u)[0];
    reinterpret_cast<uint4*>(xbp)[1] = reinterpret_cast<uint4*>(u)[1];
    reinterpret_cast<uint4*>(&T[cl * 72 + lo])[0] = reinterpret_cast<uint4*>(u)[0];
    reinterpret_cast<uint4*>(&T[cl * 72 + lo + 8])[0] = reinterpret_cast<uint4*>(u)[1];
    __syncthreads();
    const int ll = t >> 2, co = (t & 3) * 16;
    unsigned short v16[16];
    #pragma unroll
    for (int j = 0; j < 16; ++j) v16[j] = T[(co + j) * 72 + ll];
    unsigned short* xtp = xt + ((size_t)b * L_ + l0 + ll) * C_ + c0 + co;
    reinterpret_cast<uint4*>(xtp)[0] = reinterpret_cast<uint4*>(v16)[0];
    reinterpret_cast<uint4*>(xtp)[1] = reinterpret_cast<uint4*>(v16)[1];
}

// ---------------- Pass A2: cast W fp32 -> bf16 ----------------
__global__ __launch_bounds__(256) void wcast_kernel(const float* __restrict__ W,
                                                    unsigned short* __restrict__ Wb) {
    const int i = blockIdx.x * 256 + threadIdx.x;
    float4 v = reinterpret_cast<const float4*>(W)[i];
    union { unsigned short u[4]; unsigned long long ll; } o;
    o.u[0] = f2bf(v.x); o.u[1] = f2bf(v.y); o.u[2] = f2bf(v.z); o.u[3] = f2bf(v.w);
    reinterpret_cast<unsigned long long*>(Wb)[i] = o.ll;
}

// ---------------- Pass B: Q = (W x + b) * QSCALE, bf16 [(b*H+h)][l][e] ----------------
__global__ __launch_bounds__(256) void proj_kernel(const unsigned short* __restrict__ Wb,
                                                   const float* __restrict__ bq,
                                                   const unsigned short* __restrict__ xt,
                                                   unsigned short* __restrict__ qb) {
    const int lt = blockIdx.x, h = blockIdx.y, b = blockIdx.z;
    const int tid = threadIdx.x, w = tid >> 6, lane = tid & 63;
    const int lr = lane & 15, lg = lane >> 4;
    const int l = lt * 64 + w * 16 + lr;
    const int o0 = h * 64;

    f32x4 acc[4] = {};
    const unsigned short* xrow = xt + ((size_t)b * L_ + l) * C_;
    for (int ks = 0; ks < 16; ++ks) {
        bf16x8 bf = *reinterpret_cast<const bf16x8*>(xrow + ks * 32 + lg * 8);
        #pragma unroll
        for (int mt = 0; mt < 4; ++mt) {
            bf16x8 af = *reinterpret_cast<const bf16x8*>(Wb + (size_t)(o0 + mt * 16 + lr) * C_ + ks * 32 + lg * 8);
            acc[mt] = __builtin_amdgcn_mfma_f32_16x16x32_bf16(af, bf, acc[mt], 0, 0, 0);
        }
    }
    const int bh = b * H_ + h;
    unsigned short* qrow = qb + ((size_t)bh * L_ + l) * 64;
    #pragma unroll
    for (int mt = 0; mt < 4; ++mt) {
        const int e0 = mt * 16 + lg * 4;
        const float4 bb = *reinterpret_cast<const float4*>(bq + o0 + e0);
        union { unsigned short u[4]; unsigned long long ll; } o;
        o.u[0] = f2bf((acc[mt][0] + bb.x) * QSCALE);
        o.u[1] = f2bf((acc[mt][1] + bb.y) * QSCALE);
        o.u[2] = f2bf((acc[mt][2] + bb.z) * QSCALE);
        o.u[3] = f2bf((acc[mt][3] + bb.w) * QSCALE);
        *reinterpret_cast<unsigned long long*>(qrow + e0) = o.ll;
    }
}

// ---------------- Pass C: fused attention, KBLK=512, 4-bank V ring (distance 2) ----------------
// V loads for 32k-step at k-offset KOFF into bank BK (4 x b128, wave's 64 channels)
#define LDVB(BK, KOFF)                                                                  \
    {                                                                                   \
        _Pragma("unroll")                                                               \
        for (int ct = 0; ct < 4; ++ct)                                                  \
            pvv[BK][ct] = *reinterpret_cast<const bf16x8*>(                             \
                Vbase + (size_t)(c0w + ct * 16 + lr) * L_ + (KOFF) + lg * 8);           \
    }

// PV step S_: consume bank CUR, prefetch step S_+2 into bank NXT; 16 MFMAs
#define PV_STEP(CUR, NXT, S_)                                                           \
    {                                                                                   \
        const int s_ = (S_);                                                            \
        if (s_ + 2 < ksmax) LDVB(NXT, k0 + (s_ + 2) * 32)                               \
        bf16x8 pa[4];                                                                   \
        _Pragma("unroll")                                                               \
        for (int mt = 0; mt < 4; ++mt) {                                                \
            const int row = mt * 16 + lr;                                               \
            const int g2 = (s_ * 4 + lg) ^ (lr & 7);                                    \
            pa[mt] = *reinterpret_cast<const bf16x8*>(&P[row * 512 + (g2 << 3)]);       \
        }                                                                               \
        __builtin_amdgcn_s_setprio(1);                                                  \
        _Pragma("unroll")                                                               \
        for (int mt = 0; mt < 4; ++mt)                                                  \
            _Pragma("unroll")                                                           \
            for (int ct = 0; ct < 4; ++ct)                                              \
                acc[mt][ct] = __builtin_amdgcn_mfma_f32_16x16x32_bf16(                  \
                    pa[mt], pvv[CUR][ct], acc[mt][ct], 0, 0, 0);                        \
        __builtin_amdgcn_s_setprio(0);                                                  \
    }

__global__ __launch_bounds__(512, 2) void pv_kernel(const unsigned short* __restrict__ qb,
                                                    const unsigned short* __restrict__ xb,
                                                    float* __restrict__ out,
                                                    int* __restrict__ counters) {
    const int tid = threadIdx.x, w = tid >> 6, lane = tid & 63;
    const int lr = lane & 15, lg = lane >> 4;
    const int c0w = w * 64;                      // PV: this wave's 64-channel slice
    // batch pinned by blockIdx (XCD round-robin heuristic): 128 blocks per batch
    const int myb = (blockIdx.x & 7) >> 1;

    __shared__ unsigned short Qt[64 * 64];       // swizzled Q tile (8 KB)
    __shared__ unsigned short P[64 * 512];       // 64q x 512k bf16, XOR-swizzled (64 KB)
    __shared__ float rsT[64][8];                 // per-S-wave rowsum partials (2 KB)
    __shared__ int s_u;

    const int b = myb;
    const unsigned short* Vbase = xb + (size_t)b * C_ * L_;

    for (;;) {
        __syncthreads();   // previous unit's readers of Qt/P/rsT/s_u are done
        if (tid == 0) s_u = atomicAdd(counters + myb, 1);
        __syncthreads();
        const int u = s_u;
        if (u >= NUNITS_B) return;

        // heavy q-tiles first (LPT packing on the per-batch dynamic queue)
        const int qt = 31 - (u >> 3);
        const int h = u & 7;
        const int q0 = qt * 64, qlim = q0 + 63;
        const int nkt = (q0 >> 9) + 1;           // KBLK = 512
        const int bh = b * H_ + h;
        const unsigned short* Qbase = qb + (size_t)bh * L_ * 64;

        // stage Q tile (64 rows x 64 e) into LDS, granule g -> g ^ (row&7)
        {
            const int r = tid >> 3, g = tid & 7;
            bf16x8 v = *reinterpret_cast<const bf16x8*>(Qbase + (size_t)(q0 + r) * 64 + g * 8);
            *reinterpret_cast<bf16x8*>(&Qt[r * 64 + ((g ^ (r & 7)) << 3)]) = v;
        }

        bf16x8 pvv[4][4];                        // 4-bank V ring, distance-2 prefetch
        f32x4 acc[4][4] = {};
        float rs[4] = {0.f, 0.f, 0.f, 0.f};

        LBAR();   // Qt visible

        #pragma unroll 1
        for (int kt = 0; kt < nkt; ++kt) {
            const int k0 = kt * 512;
            const int ksmax = min(16, ((qlim - k0) >> 5) + 1);   // even, 2..16
            const int kw0 = k0 + w * 64;                          // S: wave's 64k slice

            // ---- S phase: wave computes 64q x 64k slice of S, exp, pack to P ----
            if (kw0 <= qlim) {
                // K A-frags: 4 ksub x 2 e-halves, direct from global
                bf16x8 kb[4][2];
                #pragma unroll
                for (int ksub = 0; ksub < 4; ++ksub) {
                    const size_t krow = (size_t)(kw0 + ksub * 16 + lr) * 64;
                    kb[ksub][0] = *reinterpret_cast<const bf16x8*>(Qbase + krow + lg * 8);
                    kb[ksub][1] = *reinterpret_cast<const bf16x8*>(Qbase + krow + 32 + lg * 8);
                }
                LDVB(0, k0)          // PV steps 0,1 V loads issued under the S phase
                LDVB(1, k0 + 32)
                #pragma unroll
                for (int nt = 0; nt < 4; ++nt) {
                    const int qrow = nt * 16 + lr;
                    bf16x8 aq0 = *reinterpret_cast<const bf16x8*>(&Qt[qrow * 64 + ((lg ^ (lr & 7)) << 3)]);
                    bf16x8 aq1 = *reinterpret_cast<const bf16x8*>(&Qt[qrow * 64 + (((4 + lg) ^ (lr & 7)) << 3)]);
                    const int q = q0 + qrow;
                    #pragma unroll
                    for (int ksub = 0; ksub < 4; ++ksub) {
                        f32x4 z = {};
                        z = __builtin_amdgcn_mfma_f32_16x16x32_bf16(kb[ksub][0], aq0, z, 0, 0, 0);
                        z = __builtin_amdgcn_mfma_f32_16x16x32_bf16(kb[ksub][1], aq1, z, 0, 0, 0);
                        const int kbase = kw0 + ksub * 16 + lg * 4;
                        const float p0 = (kbase + 0 <= q) ? exp2f(z[0]) : 0.f;
                        const float p1 = (kbase + 1 <= q) ? exp2f(z[1]) : 0.f;
                        const float p2 = (kbase + 2 <= q) ? exp2f(z[2]) : 0.f;
                        const float p3 = (kbase + 3 <= q) ? exp2f(z[3]) : 0.f;
                        rs[nt] += (p0 + p1) + (p2 + p3);
                        unsigned r01, r23;
                        asm("v_cvt_pk_bf16_f32 %0, %1, %2" : "=v"(r01) : "v"(p0), "v"(p1));
                        asm("v_cvt_pk_bf16_f32 %0, %1, %2" : "=v"(r23) : "v"(p2), "v"(p3));
                        const int kl = w * 64 + ksub * 16 + lg * 4;   // 0..511
                        const int gg = (kl >> 3) ^ (qrow & 7);
                        const unsigned long long pk = ((unsigned long long)r23 << 32) | r01;
                        *reinterpret_cast<unsigned long long*>(&P[qrow * 512 + (gg << 3) + (kl & 7)]) = pk;
                    }
                }
            } else {
                LDVB(0, k0)
                LDVB(1, k0 + 32)
            }
            LBAR();   // P visible; V bank-0/1 loads stay in flight

            // ---- PV phase: up to 16 back-to-back steps, 4-bank ring, distance 2 ----
            int s = 0;
            #pragma unroll 1
            for (; s + 4 <= ksmax; s += 4) {
                PV_STEP(0, 2, s)
                PV_STEP(1, 3, s + 1)
                PV_STEP(2, 0, s + 2)
                PV_STEP(3, 1, s + 3)
            }
            if (s < ksmax) {   // remainder 2 (s & 3 == 0 always here)
                PV_STEP(0, 2, s)
                PV_STEP(1, 3, s + 1)
            }
            LBAR();   // P consumed; next kt's S may overwrite
        }

        // rowsum: reduce over lg, publish per-wave partials, merge
        #pragma unroll
        for (int nt = 0; nt < 4; ++nt) {
            float t0 = __shfl_xor(rs[nt], 16); rs[nt] += t0;
            float t1 = __shfl_xor(rs[nt], 32); rs[nt] += t1;
        }
        if (lg == 0) {
            #pragma unroll
            for (int nt = 0; nt < 4; ++nt) rsT[nt * 16 + lr][w] = rs[nt];
        }
        LBAR();

        // epilogue: li per q, bf16 residual, NT streaming stores
        const unsigned short* xres = xb + (size_t)b * C_ * L_;
        float* ob = out + (size_t)bh * C_ * L_;
        #pragma unroll
        for (int mt = 0; mt < 4; ++mt) {
            f32x4 li;
            #pragma unroll
            for (int r = 0; r < 4; ++r) {
                const f32x4 s0 = *reinterpret_cast<const f32x4*>(&rsT[mt * 16 + lg * 4 + r][0]);
                const f32x4 s1 = *reinterpret_cast<const f32x4*>(&rsT[mt * 16 + lg * 4 + r][4]);
                li[r] = 1.f / (((s0[0] + s0[1]) + (s0[2] + s0[3])) + ((s1[0] + s1[1]) + (s1[2] + s1[3])));
            }
            const int lbase = q0 + mt * 16 + lg * 4;
            #pragma unroll
            for (int ct = 0; ct < 4; ++ct) {
                const int c = c0w + ct * 16 + lr;
                const u16x4 rv = __builtin_nontemporal_load(
                    reinterpret_cast<const u16x4*>(xres + (size_t)c * L_ + lbase));
                f32x4 o;
                o[0] = acc[mt][ct][0] * li[0] + __uint_as_float((unsigned)rv[0] << 16);
                o[1] = acc[mt][ct][1] * li[1] + __uint_as_float((unsigned)rv[1] << 16);
                o[2] = acc[mt][ct][2] * li[2] + __uint_as_float((unsigned)rv[2] << 16);
                o[3] = acc[mt][ct][3] * li[3] + __uint_as_float((unsigned)rv[3] << 16);
                __builtin_nontemporal_store(o, reinterpret_cast<f32x4*>(ob + (size_t)c * L_ + lbase));
            }
        }
    }
}

extern "C" void kernel_launch(void* const* d_in, const int* in_sizes, int n_in,
                              void* d_out, int out_size, void* d_ws, size_t ws_size,
                              hipStream_t stream) {
    const float* x  = (const float*)d_in[0];
    const float* Wq = (const float*)d_in[1];
    const float* bq = (const float*)d_in[2];
    float* out = (float*)d_out;

    unsigned short* xb   = (unsigned short*)d_ws;                        // B*C*L bf16   = 8 MiB
    unsigned short* xt   = xb + (size_t)B_ * C_ * L_;                    // B*L*C bf16   = 8 MiB
    unsigned short* qbuf = xt + (size_t)B_ * L_ * C_;                    // B*H*L*E bf16 = 8 MiB
    unsigned short* Wb   = qbuf + (size_t)B_ * H_ * L_ * E_;             // 512 KiB
    int* counters = (int*)(Wb + (size_t)H_ * E_ * C_);                   // 16 B (one per batch)

    (void)hipMemsetAsync(counters, 0, 16, stream);
    prep_kernel<<<dim3(32, 8, 4), 256, 0, stream>>>(x, xb, xt);
    wcast_kernel<<<dim3(256), 256, 0, stream>>>(Wq, Wb);
    proj_kernel<<<dim3(32, 8, 4), 256, 0, stream>>>(Wb, bq, xt, qbuf);
    pv_kernel<<<dim3(512), 512, 0, stream>>>(qbuf, xb, out, counters);
}